// Round 8
// baseline (131.495 us; speedup 1.0000x reference)
//
#include <hip/hip_runtime.h>
#include <math.h>

// DotProductAttention: B=1,H=16,S=4096,D=64, fp32 in/out, no scale.
// Phase 1: prepack K/V -> fp16 MFMA-fragment-order tiles in d_ws.
// Phase 2: attn_split -- round-4 LDS-staged structure (gload_lds, 3-buffer,
//   counted vmcnt, VGPR ~76) with CROSS-BLOCK KV-SPLIT: 512 blocks =
//   16 heads x 16 qtiles x 2 kv-halves; each block: 256 q x 2048 KV.
//   Partial (acc, m, l) written unnormalized to d_ws.
// Phase 3: merge kernel combines the two halves per (head,qtile).
// 512 blocks x 8 waves -> 2 blocks/CU, 16 waves/CU (4/SIMD): the all-register
// variant could not exceed 2/SIMD (K/V reg double-buffer ~190 regs/wave).

#define HH 16
#define SS 4096
#define DDm 64
#define KB 64
#define NTL (SS / KB)
#define NTLH 32  // tiles per KV half
#define LDP 72   // fallback kernel only

typedef __attribute__((ext_vector_type(2))) _Float16 half2_t;
typedef __attribute__((ext_vector_type(8))) _Float16 half8_t;
typedef __attribute__((ext_vector_type(16))) float f32x16;

union H8 { half2_t h2[4]; half8_t v; };
union FU { float f; unsigned u; };
union HU { half2_t h; unsigned u; };

__device__ inline unsigned asu(float x){ FU c; c.f=x; return c.u; }
__device__ inline float    asf(unsigned x){ FU c; c.u=x; return c.f; }
__device__ inline unsigned h2u(half2_t x){ HU c; c.h=x; return c.u; }
__device__ inline half2_t  u2h(unsigned x){ HU c; c.u=x; return c.h; }
__device__ inline half2_t  pk2(float a, float b){ half2_t h; h[0]=(_Float16)a; h[1]=(_Float16)b; return h; }

#if __has_builtin(__builtin_amdgcn_permlane32_swap)
#define HAVE_PL32 1
typedef __attribute__((ext_vector_type(2))) unsigned uint2_t;
__device__ inline uint2_t pl32(unsigned a, unsigned b){
  return __builtin_amdgcn_permlane32_swap(a, b, false, false);
}
#endif

#if __has_builtin(__builtin_amdgcn_exp2f)
#define EXP2F(x) __builtin_amdgcn_exp2f(x)
#else
#define EXP2F(x) exp2f(x)
#endif
#define L2E 1.44269504088896f

#define WAITVM(n) asm volatile("s_waitcnt vmcnt(" #n ")" ::: "memory")

__device__ __forceinline__ void gload16(const void* g, void* l) {
  __builtin_amdgcn_global_load_lds(
      (const __attribute__((address_space(1))) unsigned int*)g,
      (__attribute__((address_space(3))) unsigned int*)l, 16, 0, 0);
}

// ---------------- pre-pack: K/V fp32 -> fp16 fragment-order tiles ----------------
// K tile (h,t): elem (r, d=8*dg+e) at half-index (dg*64 + r)*8 + e   (8 KB/tile)
// V tile (h,t): elem (kv=8*kg+e, d_row) at (kg*64 + d_row)*8 + e     (transposed)
__global__ __launch_bounds__(256)
void prepack(const float* __restrict__ K, const float* __restrict__ V,
             _Float16* __restrict__ Kh, _Float16* __restrict__ Vth) {
  const int g = blockIdx.x;
  const int tid = threadIdx.x;
  if (g < 2048) {
    const int gt = g * 256 + tid;
    const int dg = gt & 7, r = (gt >> 3) & 63, t = (gt >> 9) & 63, h = gt >> 15;
    const float* src = K + ((size_t)(h * SS + t * 64 + r)) * DDm + dg * 8;
    float4 a = *(const float4*)src;
    float4 b = *(const float4*)(src + 4);
    H8 w;
    w.h2[0] = pk2(a.x, a.y); w.h2[1] = pk2(a.z, a.w);
    w.h2[2] = pk2(b.x, b.y); w.h2[3] = pk2(b.z, b.w);
    *(half8_t*)(Kh + (size_t)(h * 64 + t) * 4096 + (dg * 64 + r) * 8) = w.v;
  } else {
    const int gt = (g - 2048) * 256 + tid;
    const int dr = gt & 63, kg = (gt >> 6) & 7, t = (gt >> 9) & 63, h = gt >> 15;
    const float* src = V + ((size_t)(h * SS + t * 64 + kg * 8)) * DDm + dr;
    H8 w;
#pragma unroll
    for (int j = 0; j < 4; ++j)
      w.h2[j] = pk2(src[(2 * j) * DDm], src[(2 * j + 1) * DDm]);
    *(half8_t*)(Vth + (size_t)(h * 64 + t) * 4096 + (kg * 64 + dr) * 8) = w.v;
  }
}

// ---------------- split attention kernel: LDS-staged, KV half per block ----------------
__global__ __launch_bounds__(512, 2)
void attn_split(const float* __restrict__ Q, const _Float16* __restrict__ Kh,
                const _Float16* __restrict__ Vth, float* __restrict__ Pacc,
                float* __restrict__ Pml) {
  __shared__ __align__(16) _Float16 Kbuf[3][4096];
  __shared__ __align__(16) _Float16 Vbuf[3][4096];

  const int tid  = threadIdx.x;
  const int lane = tid & 63;
  const int lo5  = lane & 31;
  const int hi   = lane >> 5;
  const int wv   = tid >> 6;

  const int lid  = blockIdx.x;                       // 0..511
  const int head = 2 * (lid & 7) + ((lid >> 3) & 1); // head pair per XCD
  const int rest = lid >> 4;                         // 0..31
  const int qt   = rest & 15;
  const int half = rest >> 4;                        // KV half
  const int qbase = qt * 256 + wv * 32;
  const size_t hoff = (size_t)head * SS * DDm;

  // Q B-frags: lane holds Q[qbase+lo5][16ds+8hi+e]
  H8 qf[4];
  {
    const float* qp = Q + hoff + (size_t)(qbase + lo5) * DDm;
#pragma unroll
    for (int ds = 0; ds < 4; ++ds) {
      float4 a = *(const float4*)(qp + 16 * ds + 8 * hi);
      float4 b = *(const float4*)(qp + 16 * ds + 8 * hi + 4);
      qf[ds].h2[0] = pk2(a.x, a.y); qf[ds].h2[1] = pk2(a.z, a.w);
      qf[ds].h2[2] = pk2(b.x, b.y); qf[ds].h2[3] = pk2(b.z, b.w);
    }
  }

  const _Float16* kt0 = Kh + (size_t)head * 64 * 4096 + (size_t)half * NTLH * 4096;
  const _Float16* vt0 = Vth + (size_t)head * 64 * 4096 + (size_t)half * NTLH * 4096;

  f32x16 acc[2];
#pragma unroll
  for (int nt = 0; nt < 2; ++nt)
#pragma unroll
    for (int r = 0; r < 16; ++r) acc[nt][r] = 0.f;
  float m_run = -INFINITY, l_run = 0.f;

  // prologue: tiles 0,1 in flight
  gload16(kt0 + (size_t)tid * 8, &Kbuf[0][wv * 512]);
  gload16(vt0 + (size_t)tid * 8, &Vbuf[0][wv * 512]);
  gload16(kt0 + 4096 + (size_t)tid * 8, &Kbuf[1][wv * 512]);
  gload16(vt0 + 4096 + (size_t)tid * 8, &Vbuf[1][wv * 512]);

  int bc = 0;
  for (int t = 0; t < NTLH; ++t) {
    if (t < NTLH - 1) { WAITVM(2); } else { WAITVM(0); }
    __builtin_amdgcn_s_barrier();
    __builtin_amdgcn_sched_barrier(0);
    if (t + 2 < NTLH) {
      int bi = bc + 2; if (bi >= 3) bi -= 3;
      gload16(kt0 + (size_t)(t + 2) * 4096 + (size_t)tid * 8, &Kbuf[bi][wv * 512]);
      gload16(vt0 + (size_t)(t + 2) * 4096 + (size_t)tid * 8, &Vbuf[bi][wv * 512]);
    }

    // all fragment reads for this tile (contiguous 16B wave accesses, conflict-free)
    half8_t kf[2][4];
#pragma unroll
    for (int s = 0; s < 2; ++s)
#pragma unroll
      for (int ds = 0; ds < 4; ++ds)
        kf[s][ds] = *(const half8_t*)&Kbuf[bc][((ds * 2 + hi) * 64 + 32 * s + lo5) * 8];
    half8_t vfr[2][2][2];
#pragma unroll
    for (int s = 0; s < 2; ++s)
#pragma unroll
      for (int sp = 0; sp < 2; ++sp)
#pragma unroll
        for (int nt = 0; nt < 2; ++nt)
          vfr[s][sp][nt] = *(const half8_t*)&Vbuf[bc][(((s * 2 + sp) * 2 + hi) * 64 + nt * 32 + lo5) * 8];

#pragma unroll
    for (int s = 0; s < 2; ++s) {
      f32x16 st;
#pragma unroll
      for (int r = 0; r < 16; ++r) st[r] = 0.f;
#pragma unroll
      for (int ds = 0; ds < 4; ++ds)
        st = __builtin_amdgcn_mfma_f32_32x32x16_f16(kf[s][ds], qf[ds].v, st, 0, 0, 0);

      // tree row-max
      float a0 = fmaxf(st[0], st[1]),   a1 = fmaxf(st[2], st[3]);
      float a2 = fmaxf(st[4], st[5]),   a3 = fmaxf(st[6], st[7]);
      float a4 = fmaxf(st[8], st[9]),   a5 = fmaxf(st[10], st[11]);
      float a6 = fmaxf(st[12], st[13]), a7 = fmaxf(st[14], st[15]);
      float b0 = fmaxf(a0, a1), b1 = fmaxf(a2, a3);
      float b2 = fmaxf(a4, a5), b3 = fmaxf(a6, a7);
      float tmax = fmaxf(fmaxf(b0, b1), fmaxf(b2, b3));
#if HAVE_PL32
      { uint2_t pr = pl32(asu(tmax), asu(tmax)); tmax = fmaxf(asf(pr[0]), asf(pr[1])); }
#else
      tmax = fmaxf(tmax, __shfl_xor(tmax, 32, 64));
#endif
      // defer-max rescale (rare)
      if (__any(tmax > m_run + 8.f)) {
        float mnew = fmaxf(m_run, tmax);
        float corr = EXP2F((m_run - mnew) * L2E);
        m_run = mnew; l_run *= corr;
#pragma unroll
        for (int r = 0; r < 16; ++r) {
          const int qr = (r & 3) + 8 * (r >> 2) + 4 * hi;
          float cf = asf(__builtin_amdgcn_ds_bpermute(qr << 2, asu(corr)));
          acc[0][r] *= cf; acc[1][r] *= cf;
        }
      }

      // exp + 4-chain sum
      const float mt = m_run * L2E;
      float p[16];
      float s0 = 0.f, s1 = 0.f, s2 = 0.f, s3 = 0.f;
#pragma unroll
      for (int r = 0; r < 16; r += 4) {
        p[r]     = EXP2F(__builtin_fmaf(st[r],     L2E, -mt)); s0 += p[r];
        p[r + 1] = EXP2F(__builtin_fmaf(st[r + 1], L2E, -mt)); s1 += p[r + 1];
        p[r + 2] = EXP2F(__builtin_fmaf(st[r + 2], L2E, -mt)); s2 += p[r + 2];
        p[r + 3] = EXP2F(__builtin_fmaf(st[r + 3], L2E, -mt)); s3 += p[r + 3];
      }
      float lsum = (s0 + s1) + (s2 + s3);
#if HAVE_PL32
      { uint2_t pr = pl32(asu(lsum), asu(lsum)); lsum = asf(pr[0]) + asf(pr[1]); }
#else
      lsum += __shfl_xor(lsum, 32, 64);
#endif
      l_run += lsum;

      // pack P -> PV A-frags
      H8 pa[2];
#pragma unroll
      for (int step = 0; step < 2; ++step) {
        const int b = 8 * step;
        half2_t x0 = pk2(p[b + 0], p[b + 1]);
        half2_t x1 = pk2(p[b + 2], p[b + 3]);
        half2_t y0 = pk2(p[b + 4], p[b + 5]);
        half2_t y1 = pk2(p[b + 6], p[b + 7]);
#if HAVE_PL32
        uint2_t sA = pl32(h2u(x0), h2u(y0));
        uint2_t sB = pl32(h2u(x1), h2u(y1));
        pa[step].h2[0] = u2h(sA[0]); pa[step].h2[1] = u2h(sB[0]);
        pa[step].h2[2] = u2h(sA[1]); pa[step].h2[3] = u2h(sB[1]);
#else
        half2_t sx0 = u2h(__shfl_xor(h2u(x0), 32, 64));
        half2_t sx1 = u2h(__shfl_xor(h2u(x1), 32, 64));
        half2_t sy0 = u2h(__shfl_xor(h2u(y0), 32, 64));
        half2_t sy1 = u2h(__shfl_xor(h2u(y1), 32, 64));
        pa[step].h2[0] = hi ? sy0 : x0;  pa[step].h2[1] = hi ? sy1 : x1;
        pa[step].h2[2] = hi ? y0 : sx0;  pa[step].h2[3] = hi ? y1 : sx1;
#endif
      }
#pragma unroll
      for (int step = 0; step < 2; ++step)
#pragma unroll
        for (int nt = 0; nt < 2; ++nt)
          acc[nt] = __builtin_amdgcn_mfma_f32_32x32x16_f16(pa[step].v, vfr[s][step][nt], acc[nt], 0, 0, 0);
    }

    bc += 1; if (bc >= 3) bc = 0;
  }

  // ---- epilogue: store unnormalized partials ----
  const int pidx = (head * 16 + qt) * 2 + half;
  float* pa = Pacc + (size_t)pidx * 16384;  // [q 256][d 64]
#pragma unroll
  for (int r = 0; r < 16; ++r) {
    const int qr = (r & 3) + 8 * (r >> 2) + 4 * hi;
    float* op = pa + (wv * 32 + qr) * 64 + lo5;
    op[0]  = acc[0][r];
    op[32] = acc[1][r];
  }
  if (hi == 0) {
    Pml[(size_t)pidx * 512 + wv * 32 + lo5]       = m_run;
    Pml[(size_t)pidx * 512 + 256 + wv * 32 + lo5] = l_run;
  }
}

// ---------------- merge kernel: combine the two KV halves ----------------
__global__ __launch_bounds__(256)
void merge_halves(const float* __restrict__ Pacc, const float* __restrict__ Pml,
                  float* __restrict__ O) {
  const int e  = (blockIdx.x * 256 + threadIdx.x) * 4;  // grid 4096
  const int d4 = e & 63;
  const int q  = (e >> 6) & 255;
  const int p  = e >> 14;          // head*16 + qt, 0..255
  const float m0 = Pml[(size_t)(p * 2) * 512 + q];
  const float l0 = Pml[(size_t)(p * 2) * 512 + 256 + q];
  const float m1 = Pml[(size_t)(p * 2 + 1) * 512 + q];
  const float l1 = Pml[(size_t)(p * 2 + 1) * 512 + 256 + q];
  const float m  = fmaxf(m0, m1);
  const float e0 = EXP2F((m0 - m) * L2E);
  const float e1 = EXP2F((m1 - m) * L2E);
  const float inv = 1.f / (e0 * l0 + e1 * l1);
  const float f0 = e0 * inv, f1 = e1 * inv;
  float4 x0 = *(const float4*)(Pacc + (size_t)(p * 2) * 16384 + q * 64 + d4);
  float4 x1 = *(const float4*)(Pacc + (size_t)(p * 2 + 1) * 16384 + q * 64 + d4);
  float4 o;
  o.x = x0.x * f0 + x1.x * f1;
  o.y = x0.y * f0 + x1.y * f1;
  o.z = x0.z * f0 + x1.z * f1;
  o.w = x0.w * f0 + x1.w * f1;
  const int head = p >> 4, qt = p & 15;
  *(float4*)(O + ((size_t)head * SS + qt * 256 + q) * DDm + d4) = o;
}

// ---------------- mid fallback: round-4 full-KV kernel (ws >= 16MB only) ----------------
__global__ __launch_bounds__(512, 2)
void attn_full(const float* __restrict__ Q, const _Float16* __restrict__ Kh,
               const _Float16* __restrict__ Vth, float* __restrict__ O) {
  __shared__ __align__(16) _Float16 Kbuf[3][4096];
  __shared__ __align__(16) _Float16 Vbuf[3][4096];

  const int tid  = threadIdx.x;
  const int lane = tid & 63;
  const int lo5  = lane & 31;
  const int hi   = lane >> 5;
  const int wv   = tid >> 6;

  const int lid  = blockIdx.x;
  const int head = 2 * (lid & 7) + ((lid >> 3) & 1);
  const int qt   = lid >> 4;
  const int qbase = qt * 256 + wv * 32;
  const size_t hoff = (size_t)head * SS * DDm;

  H8 qf[4];
  {
    const float* qp = Q + hoff + (size_t)(qbase + lo5) * DDm;
#pragma unroll
    for (int ds = 0; ds < 4; ++ds) {
      float4 a = *(const float4*)(qp + 16 * ds + 8 * hi);
      float4 b = *(const float4*)(qp + 16 * ds + 8 * hi + 4);
      qf[ds].h2[0] = pk2(a.x, a.y); qf[ds].h2[1] = pk2(a.z, a.w);
      qf[ds].h2[2] = pk2(b.x, b.y); qf[ds].h2[3] = pk2(b.z, b.w);
    }
  }

  const _Float16* kt0 = Kh + (size_t)head * 64 * 4096;
  const _Float16* vt0 = Vth + (size_t)head * 64 * 4096;

  f32x16 acc[2];
#pragma unroll
  for (int nt = 0; nt < 2; ++nt)
#pragma unroll
    for (int r = 0; r < 16; ++r) acc[nt][r] = 0.f;
  float m_run = -INFINITY, l_run = 0.f;

  gload16(kt0 + (size_t)tid * 8, &Kbuf[0][wv * 512]);
  gload16(vt0 + (size_t)tid * 8, &Vbuf[0][wv * 512]);
  gload16(kt0 + 4096 + (size_t)tid * 8, &Kbuf[1][wv * 512]);
  gload16(vt0 + 4096 + (size_t)tid * 8, &Vbuf[1][wv * 512]);

  int bc = 0;
  for (int t = 0; t < NTL; ++t) {
    if (t < NTL - 1) { WAITVM(2); } else { WAITVM(0); }
    __builtin_amdgcn_s_barrier();
    __builtin_amdgcn_sched_barrier(0);
    if (t + 2 < NTL) {
      int bi = bc + 2; if (bi >= 3) bi -= 3;
      gload16(kt0 + (size_t)(t + 2) * 4096 + (size_t)tid * 8, &Kbuf[bi][wv * 512]);
      gload16(vt0 + (size_t)(t + 2) * 4096 + (size_t)tid * 8, &Vbuf[bi][wv * 512]);
    }

    half8_t kf[2][4];
#pragma unroll
    for (int s = 0; s < 2; ++s)
#pragma unroll
      for (int ds = 0; ds < 4; ++ds)
        kf[s][ds] = *(const half8_t*)&Kbuf[bc][((ds * 2 + hi) * 64 + 32 * s + lo5) * 8];
    half8_t vfr[2][2][2];
#pragma unroll
    for (int s = 0; s < 2; ++s)
#pragma unroll
      for (int sp = 0; sp < 2; ++sp)
#pragma unroll
        for (int nt = 0; nt < 2; ++nt)
          vfr[s][sp][nt] = *(const half8_t*)&Vbuf[bc][(((s * 2 + sp) * 2 + hi) * 64 + nt * 32 + lo5) * 8];

#pragma unroll
    for (int s = 0; s < 2; ++s) {
      f32x16 st;
#pragma unroll
      for (int r = 0; r < 16; ++r) st[r] = 0.f;
#pragma unroll
      for (int ds = 0; ds < 4; ++ds)
        st = __builtin_amdgcn_mfma_f32_32x32x16_f16(kf[s][ds], qf[ds].v, st, 0, 0, 0);

      float a0 = fmaxf(st[0], st[1]),   a1 = fmaxf(st[2], st[3]);
      float a2 = fmaxf(st[4], st[5]),   a3 = fmaxf(st[6], st[7]);
      float a4 = fmaxf(st[8], st[9]),   a5 = fmaxf(st[10], st[11]);
      float a6 = fmaxf(st[12], st[13]), a7 = fmaxf(st[14], st[15]);
      float b0 = fmaxf(a0, a1), b1 = fmaxf(a2, a3);
      float b2 = fmaxf(a4, a5), b3 = fmaxf(a6, a7);
      float tmax = fmaxf(fmaxf(b0, b1), fmaxf(b2, b3));
#if HAVE_PL32
      { uint2_t pr = pl32(asu(tmax), asu(tmax)); tmax = fmaxf(asf(pr[0]), asf(pr[1])); }
#else
      tmax = fmaxf(tmax, __shfl_xor(tmax, 32, 64));
#endif
      if (__any(tmax > m_run + 8.f)) {
        float mnew = fmaxf(m_run, tmax);
        float corr = EXP2F((m_run - mnew) * L2E);
        m_run = mnew; l_run *= corr;
#pragma unroll
        for (int r = 0; r < 16; ++r) {
          const int qr = (r & 3) + 8 * (r >> 2) + 4 * hi;
          float cf = asf(__builtin_amdgcn_ds_bpermute(qr << 2, asu(corr)));
          acc[0][r] *= cf; acc[1][r] *= cf;
        }
      }

      const float mt = m_run * L2E;
      float p[16];
      float s0 = 0.f, s1 = 0.f, s2 = 0.f, s3 = 0.f;
#pragma unroll
      for (int r = 0; r < 16; r += 4) {
        p[r]     = EXP2F(__builtin_fmaf(st[r],     L2E, -mt)); s0 += p[r];
        p[r + 1] = EXP2F(__builtin_fmaf(st[r + 1], L2E, -mt)); s1 += p[r + 1];
        p[r + 2] = EXP2F(__builtin_fmaf(st[r + 2], L2E, -mt)); s2 += p[r + 2];
        p[r + 3] = EXP2F(__builtin_fmaf(st[r + 3], L2E, -mt)); s3 += p[r + 3];
      }
      float lsum = (s0 + s1) + (s2 + s3);
#if HAVE_PL32
      { uint2_t pr = pl32(asu(lsum), asu(lsum)); lsum = asf(pr[0]) + asf(pr[1]); }
#else
      lsum += __shfl_xor(lsum, 32, 64);
#endif
      l_run += lsum;

      H8 pa[2];
#pragma unroll
      for (int step = 0; step < 2; ++step) {
        const int b = 8 * step;
        half2_t x0 = pk2(p[b + 0], p[b + 1]);
        half2_t x1 = pk2(p[b + 2], p[b + 3]);
        half2_t y0 = pk2(p[b + 4], p[b + 5]);
        half2_t y1 = pk2(p[b + 6], p[b + 7]);
#if HAVE_PL32
        uint2_t sA = pl32(h2u(x0), h2u(y0));
        uint2_t sB = pl32(h2u(x1), h2u(y1));
        pa[step].h2[0] = u2h(sA[0]); pa[step].h2[1] = u2h(sB[0]);
        pa[step].h2[2] = u2h(sA[1]); pa[step].h2[3] = u2h(sB[1]);
#else
        half2_t sx0 = u2h(__shfl_xor(h2u(x0), 32, 64));
        half2_t sx1 = u2h(__shfl_xor(h2u(x1), 32, 64));
        half2_t sy0 = u2h(__shfl_xor(h2u(y0), 32, 64));
        half2_t sy1 = u2h(__shfl_xor(h2u(y1), 32, 64));
        pa[step].h2[0] = hi ? sy0 : x0;  pa[step].h2[1] = hi ? sy1 : x1;
        pa[step].h2[2] = hi ? y0 : sx0;  pa[step].h2[3] = hi ? y1 : sx1;
#endif
      }
#pragma unroll
      for (int step = 0; step < 2; ++step)
#pragma unroll
        for (int nt = 0; nt < 2; ++nt)
          acc[nt] = __builtin_amdgcn_mfma_f32_32x32x16_f16(pa[step].v, vfr[s][step][nt], acc[nt], 0, 0, 0);
    }

    bc += 1; if (bc >= 3) bc = 0;
  }

  const float invl = 1.f / l_run;
#pragma unroll
  for (int r = 0; r < 16; ++r) {
    const int qr = (r & 3) + 8 * (r >> 2) + 4 * hi;
    float il = asf(__builtin_amdgcn_ds_bpermute(qr << 2, asu(invl)));
    float* op = O + hoff + (size_t)(qbase + qr) * DDm + lo5;
    op[0]  = acc[0][r] * il;
    op[32] = acc[1][r] * il;
  }
}

extern "C" void kernel_launch(void* const* d_in, const int* in_sizes, int n_in,
                              void* d_out, int out_size, void* d_ws, size_t ws_size,
                              hipStream_t stream) {
  const float* Q = (const float*)d_in[0];
  const float* K = (const float*)d_in[1];
  const float* V = (const float*)d_in[2];
  float* O = (float*)d_out;

  const size_t n_kv   = (size_t)HH * SS * DDm;          // 4 Mi elems
  const size_t sz_pre = 2 * n_kv * sizeof(_Float16);    // 16 MiB
  const size_t sz_acc = (size_t)512 * 16384 * 4;        // 32 MiB
  const size_t sz_ml  = (size_t)512 * 512 * 4;          // 1 MiB

  if (ws_size >= sz_pre + sz_acc + sz_ml) {
    _Float16* Kh  = (_Float16*)d_ws;
    _Float16* Vth = Kh + n_kv;
    float* Pacc = (float*)((char*)d_ws + sz_pre);
    float* Pml  = (float*)((char*)d_ws + sz_pre + sz_acc);
    prepack<<<dim3(4096), dim3(256), 0, stream>>>(K, V, Kh, Vth);
    attn_split<<<dim3(512), dim3(512), 0, stream>>>(Q, Kh, Vth, Pacc, Pml);
    merge_halves<<<dim3(4096), dim3(256), 0, stream>>>(Pacc, Pml, O);
  } else if (ws_size >= sz_pre) {
    _Float16* Kh  = (_Float16*)d_ws;
    _Float16* Vth = Kh + n_kv;
    prepack<<<dim3(4096), dim3(256), 0, stream>>>(K, V, Kh, Vth);
    attn_full<<<dim3(256), dim3(512), 0, stream>>>(Q, Kh, Vth, O);
  }
}

// Round 9
// 117.501 us; speedup vs baseline: 1.1191x; 1.1191x over previous
//
#include <hip/hip_runtime.h>
#include <math.h>

// DotProductAttention: B=1,H=16,S=4096,D=64, fp32 in/out, no scale.
// Phase 1: prepack K/V -> fp16 MFMA-fragment-order tiles in d_ws.
// Phase 2: attn_split -- LDS-staged (gload_lds, 3-buffer, counted vmcnt),
//   cross-block KV-split: 512 blocks = 16 heads x 16 qtiles x 2 kv-halves.
//   REGISTER-LEAN: launch_bounds(512,4) caps unified VGPR+AGPR at 128/wave so
//   2 blocks/CU (16 waves, 4/SIMD) actually co-reside; K/V fragments are read
//   per-phase (not hoisted) to keep peak live regs ~100.
// Phase 3: merge kernel combines the two halves per (head,qtile).

#define HH 16
#define SS 4096
#define DDm 64
#define KB 64
#define NTL (SS / KB)
#define NTLH 32  // tiles per KV half

typedef __attribute__((ext_vector_type(2))) _Float16 half2_t;
typedef __attribute__((ext_vector_type(8))) _Float16 half8_t;
typedef __attribute__((ext_vector_type(16))) float f32x16;

union H8 { half2_t h2[4]; half8_t v; };
union FU { float f; unsigned u; };
union HU { half2_t h; unsigned u; };

__device__ inline unsigned asu(float x){ FU c; c.f=x; return c.u; }
__device__ inline float    asf(unsigned x){ FU c; c.u=x; return c.f; }
__device__ inline unsigned h2u(half2_t x){ HU c; c.h=x; return c.u; }
__device__ inline half2_t  u2h(unsigned x){ HU c; c.u=x; return c.h; }
__device__ inline half2_t  pk2(float a, float b){ half2_t h; h[0]=(_Float16)a; h[1]=(_Float16)b; return h; }

#if __has_builtin(__builtin_amdgcn_permlane32_swap)
#define HAVE_PL32 1
typedef __attribute__((ext_vector_type(2))) unsigned uint2_t;
__device__ inline uint2_t pl32(unsigned a, unsigned b){
  return __builtin_amdgcn_permlane32_swap(a, b, false, false);
}
#endif

#if __has_builtin(__builtin_amdgcn_exp2f)
#define EXP2F(x) __builtin_amdgcn_exp2f(x)
#else
#define EXP2F(x) exp2f(x)
#endif
#define L2E 1.44269504088896f

#define WAITVM(n) asm volatile("s_waitcnt vmcnt(" #n ")" ::: "memory")

__device__ __forceinline__ void gload16(const void* g, void* l) {
  __builtin_amdgcn_global_load_lds(
      (const __attribute__((address_space(1))) unsigned int*)g,
      (__attribute__((address_space(3))) unsigned int*)l, 16, 0, 0);
}

// ---------------- pre-pack: K/V fp32 -> fp16 fragment-order tiles ----------------
// K tile (h,t): elem (r, d=8*dg+e) at half-index (dg*64 + r)*8 + e   (8 KB/tile)
// V tile (h,t): elem (kv=8*kg+e, d_row) at (kg*64 + d_row)*8 + e     (transposed)
__global__ __launch_bounds__(256)
void prepack(const float* __restrict__ K, const float* __restrict__ V,
             _Float16* __restrict__ Kh, _Float16* __restrict__ Vth) {
  const int g = blockIdx.x;
  const int tid = threadIdx.x;
  if (g < 2048) {
    const int gt = g * 256 + tid;
    const int dg = gt & 7, r = (gt >> 3) & 63, t = (gt >> 9) & 63, h = gt >> 15;
    const float* src = K + ((size_t)(h * SS + t * 64 + r)) * DDm + dg * 8;
    float4 a = *(const float4*)src;
    float4 b = *(const float4*)(src + 4);
    H8 w;
    w.h2[0] = pk2(a.x, a.y); w.h2[1] = pk2(a.z, a.w);
    w.h2[2] = pk2(b.x, b.y); w.h2[3] = pk2(b.z, b.w);
    *(half8_t*)(Kh + (size_t)(h * 64 + t) * 4096 + (dg * 64 + r) * 8) = w.v;
  } else {
    const int gt = (g - 2048) * 256 + tid;
    const int dr = gt & 63, kg = (gt >> 6) & 7, t = (gt >> 9) & 63, h = gt >> 15;
    const float* src = V + ((size_t)(h * SS + t * 64 + kg * 8)) * DDm + dr;
    H8 w;
#pragma unroll
    for (int j = 0; j < 4; ++j)
      w.h2[j] = pk2(src[(2 * j) * DDm], src[(2 * j + 1) * DDm]);
    *(half8_t*)(Vth + (size_t)(h * 64 + t) * 4096 + (kg * 64 + dr) * 8) = w.v;
  }
}

// ---------------- split attention kernel: LDS-staged, register-lean ----------------
__global__ __launch_bounds__(512, 4)
void attn_split(const float* __restrict__ Q, const _Float16* __restrict__ Kh,
                const _Float16* __restrict__ Vth, float* __restrict__ Pacc,
                float* __restrict__ Pml) {
  __shared__ __align__(16) _Float16 Kbuf[3][4096];
  __shared__ __align__(16) _Float16 Vbuf[3][4096];

  const int tid  = threadIdx.x;
  const int lane = tid & 63;
  const int lo5  = lane & 31;
  const int hi   = lane >> 5;
  const int wv   = tid >> 6;

  const int lid  = blockIdx.x;                       // 0..511
  const int head = 2 * (lid & 7) + ((lid >> 3) & 1); // head pair per XCD
  const int rest = lid >> 4;                         // 0..31
  const int qt   = rest & 15;
  const int half = rest >> 4;                        // KV half
  const int qbase = qt * 256 + wv * 32;
  const size_t hoff = (size_t)head * SS * DDm;

  // Q B-frags: lane holds Q[qbase+lo5][16ds+8hi+e]
  H8 qf[4];
  {
    const float* qp = Q + hoff + (size_t)(qbase + lo5) * DDm;
#pragma unroll
    for (int ds = 0; ds < 4; ++ds) {
      float4 a = *(const float4*)(qp + 16 * ds + 8 * hi);
      float4 b = *(const float4*)(qp + 16 * ds + 8 * hi + 4);
      qf[ds].h2[0] = pk2(a.x, a.y); qf[ds].h2[1] = pk2(a.z, a.w);
      qf[ds].h2[2] = pk2(b.x, b.y); qf[ds].h2[3] = pk2(b.z, b.w);
    }
  }

  const _Float16* kt0 = Kh + (size_t)head * 64 * 4096 + (size_t)half * NTLH * 4096;
  const _Float16* vt0 = Vth + (size_t)head * 64 * 4096 + (size_t)half * NTLH * 4096;

  // per-lane LDS fragment byte offsets (in halfs)
  const int fb = (hi * 64 + lo5) * 8;  // + ds*1024 (+ s*256) for K; + (2s+sp)*1024 + nt*256 for V

  f32x16 acc[2];
#pragma unroll
  for (int nt = 0; nt < 2; ++nt)
#pragma unroll
    for (int r = 0; r < 16; ++r) acc[nt][r] = 0.f;
  float m_run = -INFINITY, l_run = 0.f;

  // prologue: tiles 0,1 in flight
  gload16(kt0 + (size_t)tid * 8, &Kbuf[0][wv * 512]);
  gload16(vt0 + (size_t)tid * 8, &Vbuf[0][wv * 512]);
  gload16(kt0 + 4096 + (size_t)tid * 8, &Kbuf[1][wv * 512]);
  gload16(vt0 + 4096 + (size_t)tid * 8, &Vbuf[1][wv * 512]);

  int bc = 0;
  for (int t = 0; t < NTLH; ++t) {
    if (t < NTLH - 1) { WAITVM(2); } else { WAITVM(0); }
    __builtin_amdgcn_s_barrier();
    __builtin_amdgcn_sched_barrier(0);
    if (t + 2 < NTLH) {
      int bi = bc + 2; if (bi >= 3) bi -= 3;
      gload16(kt0 + (size_t)(t + 2) * 4096 + (size_t)tid * 8, &Kbuf[bi][wv * 512]);
      gload16(vt0 + (size_t)(t + 2) * 4096 + (size_t)tid * 8, &Vbuf[bi][wv * 512]);
    }

#pragma unroll
    for (int s = 0; s < 2; ++s) {
      // K fragments for this 32-kv step only (16 regs live)
      f32x16 st;
#pragma unroll
      for (int r = 0; r < 16; ++r) st[r] = 0.f;
#pragma unroll
      for (int ds = 0; ds < 4; ++ds) {
        half8_t kf = *(const half8_t*)&Kbuf[bc][ds * 1024 + s * 256 + fb];
        st = __builtin_amdgcn_mfma_f32_32x32x16_f16(kf, qf[ds].v, st, 0, 0, 0);
      }

      // tree row-max
      float a0 = fmaxf(st[0], st[1]),   a1 = fmaxf(st[2], st[3]);
      float a2 = fmaxf(st[4], st[5]),   a3 = fmaxf(st[6], st[7]);
      float a4 = fmaxf(st[8], st[9]),   a5 = fmaxf(st[10], st[11]);
      float a6 = fmaxf(st[12], st[13]), a7 = fmaxf(st[14], st[15]);
      float b0 = fmaxf(a0, a1), b1 = fmaxf(a2, a3);
      float b2 = fmaxf(a4, a5), b3 = fmaxf(a6, a7);
      float tmax = fmaxf(fmaxf(b0, b1), fmaxf(b2, b3));
#if HAVE_PL32
      { uint2_t pr = pl32(asu(tmax), asu(tmax)); tmax = fmaxf(asf(pr[0]), asf(pr[1])); }
#else
      tmax = fmaxf(tmax, __shfl_xor(tmax, 32, 64));
#endif
      // defer-max rescale (rare)
      if (__any(tmax > m_run + 8.f)) {
        float mnew = fmaxf(m_run, tmax);
        float corr = EXP2F((m_run - mnew) * L2E);
        m_run = mnew; l_run *= corr;
#pragma unroll
        for (int r = 0; r < 16; ++r) {
          const int qr = (r & 3) + 8 * (r >> 2) + 4 * hi;
          float cf = asf(__builtin_amdgcn_ds_bpermute(qr << 2, asu(corr)));
          acc[0][r] *= cf; acc[1][r] *= cf;
        }
      }

      // exp in place + 4-chain sum
      const float mt = m_run * L2E;
      float s0 = 0.f, s1 = 0.f, s2 = 0.f, s3 = 0.f;
#pragma unroll
      for (int r = 0; r < 16; r += 4) {
        st[r]     = EXP2F(__builtin_fmaf(st[r],     L2E, -mt)); s0 += st[r];
        st[r + 1] = EXP2F(__builtin_fmaf(st[r + 1], L2E, -mt)); s1 += st[r + 1];
        st[r + 2] = EXP2F(__builtin_fmaf(st[r + 2], L2E, -mt)); s2 += st[r + 2];
        st[r + 3] = EXP2F(__builtin_fmaf(st[r + 3], L2E, -mt)); s3 += st[r + 3];
      }
      float lsum = (s0 + s1) + (s2 + s3);
#if HAVE_PL32
      { uint2_t pr = pl32(asu(lsum), asu(lsum)); lsum = asf(pr[0]) + asf(pr[1]); }
#else
      lsum += __shfl_xor(lsum, 32, 64);
#endif
      l_run += lsum;

      // pack P -> PV A-frags, then PV with per-step V reads (16 regs live)
#pragma unroll
      for (int step = 0; step < 2; ++step) {
        const int b = 8 * step;
        half2_t x0 = pk2(st[b + 0], st[b + 1]);
        half2_t x1 = pk2(st[b + 2], st[b + 3]);
        half2_t y0 = pk2(st[b + 4], st[b + 5]);
        half2_t y1 = pk2(st[b + 6], st[b + 7]);
        H8 pa;
#if HAVE_PL32
        uint2_t sA = pl32(h2u(x0), h2u(y0));
        uint2_t sB = pl32(h2u(x1), h2u(y1));
        pa.h2[0] = u2h(sA[0]); pa.h2[1] = u2h(sB[0]);
        pa.h2[2] = u2h(sA[1]); pa.h2[3] = u2h(sB[1]);
#else
        half2_t sx0 = u2h(__shfl_xor(h2u(x0), 32, 64));
        half2_t sx1 = u2h(__shfl_xor(h2u(x1), 32, 64));
        half2_t sy0 = u2h(__shfl_xor(h2u(y0), 32, 64));
        half2_t sy1 = u2h(__shfl_xor(h2u(y1), 32, 64));
        pa.h2[0] = hi ? sy0 : x0;  pa.h2[1] = hi ? sy1 : x1;
        pa.h2[2] = hi ? y0 : sx0;  pa.h2[3] = hi ? y1 : sx1;
#endif
#pragma unroll
        for (int nt = 0; nt < 2; ++nt) {
          half8_t vf = *(const half8_t*)&Vbuf[bc][(s * 2 + step) * 1024 + nt * 256 + fb];
          acc[nt] = __builtin_amdgcn_mfma_f32_32x32x16_f16(pa.v, vf, acc[nt], 0, 0, 0);
        }
      }
    }

    bc += 1; if (bc >= 3) bc = 0;
  }

  // ---- epilogue: store unnormalized partials ----
  const int pidx = (head * 16 + qt) * 2 + half;
  float* pa = Pacc + (size_t)pidx * 16384;  // [q 256][d 64]
#pragma unroll
  for (int r = 0; r < 16; ++r) {
    const int qr = (r & 3) + 8 * (r >> 2) + 4 * hi;
    float* op = pa + (wv * 32 + qr) * 64 + lo5;
    op[0]  = acc[0][r];
    op[32] = acc[1][r];
  }
  if (hi == 0) {
    Pml[(size_t)pidx * 512 + wv * 32 + lo5]       = m_run;
    Pml[(size_t)pidx * 512 + 256 + wv * 32 + lo5] = l_run;
  }
}

// ---------------- merge kernel: combine the two KV halves ----------------
__global__ __launch_bounds__(256)
void merge_halves(const float* __restrict__ Pacc, const float* __restrict__ Pml,
                  float* __restrict__ O) {
  const int e  = (blockIdx.x * 256 + threadIdx.x) * 4;  // grid 4096
  const int d4 = e & 63;
  const int q  = (e >> 6) & 255;
  const int p  = e >> 14;          // head*16 + qt, 0..255
  const float m0 = Pml[(size_t)(p * 2) * 512 + q];
  const float l0 = Pml[(size_t)(p * 2) * 512 + 256 + q];
  const float m1 = Pml[(size_t)(p * 2 + 1) * 512 + q];
  const float l1 = Pml[(size_t)(p * 2 + 1) * 512 + 256 + q];
  const float m  = fmaxf(m0, m1);
  const float e0 = EXP2F((m0 - m) * L2E);
  const float e1 = EXP2F((m1 - m) * L2E);
  const float inv = 1.f / (e0 * l0 + e1 * l1);
  const float f0 = e0 * inv, f1 = e1 * inv;
  float4 x0 = *(const float4*)(Pacc + (size_t)(p * 2) * 16384 + q * 64 + d4);
  float4 x1 = *(const float4*)(Pacc + (size_t)(p * 2 + 1) * 16384 + q * 64 + d4);
  float4 o;
  o.x = x0.x * f0 + x1.x * f1;
  o.y = x0.y * f0 + x1.y * f1;
  o.z = x0.z * f0 + x1.z * f1;
  o.w = x0.w * f0 + x1.w * f1;
  const int head = p >> 4, qt = p & 15;
  *(float4*)(O + ((size_t)head * SS + qt * 256 + q) * DDm + d4) = o;
}

// ---------------- fallback: round-4 full-KV kernel (ws >= 16MB only) ----------------
__global__ __launch_bounds__(512, 2)
void attn_full(const float* __restrict__ Q, const _Float16* __restrict__ Kh,
               const _Float16* __restrict__ Vth, float* __restrict__ O) {
  __shared__ __align__(16) _Float16 Kbuf[3][4096];
  __shared__ __align__(16) _Float16 Vbuf[3][4096];

  const int tid  = threadIdx.x;
  const int lane = tid & 63;
  const int lo5  = lane & 31;
  const int hi   = lane >> 5;
  const int wv   = tid >> 6;

  const int lid  = blockIdx.x;
  const int head = 2 * (lid & 7) + ((lid >> 3) & 1);
  const int qt   = lid >> 4;
  const int qbase = qt * 256 + wv * 32;
  const size_t hoff = (size_t)head * SS * DDm;

  H8 qf[4];
  {
    const float* qp = Q + hoff + (size_t)(qbase + lo5) * DDm;
#pragma unroll
    for (int ds = 0; ds < 4; ++ds) {
      float4 a = *(const float4*)(qp + 16 * ds + 8 * hi);
      float4 b = *(const float4*)(qp + 16 * ds + 8 * hi + 4);
      qf[ds].h2[0] = pk2(a.x, a.y); qf[ds].h2[1] = pk2(a.z, a.w);
      qf[ds].h2[2] = pk2(b.x, b.y); qf[ds].h2[3] = pk2(b.z, b.w);
    }
  }

  const _Float16* kt0 = Kh + (size_t)head * 64 * 4096;
  const _Float16* vt0 = Vth + (size_t)head * 64 * 4096;
  const int fb = (hi * 64 + lo5) * 8;

  f32x16 acc[2];
#pragma unroll
  for (int nt = 0; nt < 2; ++nt)
#pragma unroll
    for (int r = 0; r < 16; ++r) acc[nt][r] = 0.f;
  float m_run = -INFINITY, l_run = 0.f;

  gload16(kt0 + (size_t)tid * 8, &Kbuf[0][wv * 512]);
  gload16(vt0 + (size_t)tid * 8, &Vbuf[0][wv * 512]);
  gload16(kt0 + 4096 + (size_t)tid * 8, &Kbuf[1][wv * 512]);
  gload16(vt0 + 4096 + (size_t)tid * 8, &Vbuf[1][wv * 512]);

  int bc = 0;
  for (int t = 0; t < NTL; ++t) {
    if (t < NTL - 1) { WAITVM(2); } else { WAITVM(0); }
    __builtin_amdgcn_s_barrier();
    __builtin_amdgcn_sched_barrier(0);
    if (t + 2 < NTL) {
      int bi = bc + 2; if (bi >= 3) bi -= 3;
      gload16(kt0 + (size_t)(t + 2) * 4096 + (size_t)tid * 8, &Kbuf[bi][wv * 512]);
      gload16(vt0 + (size_t)(t + 2) * 4096 + (size_t)tid * 8, &Vbuf[bi][wv * 512]);
    }

#pragma unroll
    for (int s = 0; s < 2; ++s) {
      f32x16 st;
#pragma unroll
      for (int r = 0; r < 16; ++r) st[r] = 0.f;
#pragma unroll
      for (int ds = 0; ds < 4; ++ds) {
        half8_t kf = *(const half8_t*)&Kbuf[bc][ds * 1024 + s * 256 + fb];
        st = __builtin_amdgcn_mfma_f32_32x32x16_f16(kf, qf[ds].v, st, 0, 0, 0);
      }

      float a0 = fmaxf(st[0], st[1]),   a1 = fmaxf(st[2], st[3]);
      float a2 = fmaxf(st[4], st[5]),   a3 = fmaxf(st[6], st[7]);
      float a4 = fmaxf(st[8], st[9]),   a5 = fmaxf(st[10], st[11]);
      float a6 = fmaxf(st[12], st[13]), a7 = fmaxf(st[14], st[15]);
      float b0 = fmaxf(a0, a1), b1 = fmaxf(a2, a3);
      float b2 = fmaxf(a4, a5), b3 = fmaxf(a6, a7);
      float tmax = fmaxf(fmaxf(b0, b1), fmaxf(b2, b3));
#if HAVE_PL32
      { uint2_t pr = pl32(asu(tmax), asu(tmax)); tmax = fmaxf(asf(pr[0]), asf(pr[1])); }
#else
      tmax = fmaxf(tmax, __shfl_xor(tmax, 32, 64));
#endif
      if (__any(tmax > m_run + 8.f)) {
        float mnew = fmaxf(m_run, tmax);
        float corr = EXP2F((m_run - mnew) * L2E);
        m_run = mnew; l_run *= corr;
#pragma unroll
        for (int r = 0; r < 16; ++r) {
          const int qr = (r & 3) + 8 * (r >> 2) + 4 * hi;
          float cf = asf(__builtin_amdgcn_ds_bpermute(qr << 2, asu(corr)));
          acc[0][r] *= cf; acc[1][r] *= cf;
        }
      }

      const float mt = m_run * L2E;
      float s0 = 0.f, s1 = 0.f, s2 = 0.f, s3 = 0.f;
#pragma unroll
      for (int r = 0; r < 16; r += 4) {
        st[r]     = EXP2F(__builtin_fmaf(st[r],     L2E, -mt)); s0 += st[r];
        st[r + 1] = EXP2F(__builtin_fmaf(st[r + 1], L2E, -mt)); s1 += st[r + 1];
        st[r + 2] = EXP2F(__builtin_fmaf(st[r + 2], L2E, -mt)); s2 += st[r + 2];
        st[r + 3] = EXP2F(__builtin_fmaf(st[r + 3], L2E, -mt)); s3 += st[r + 3];
      }
      float lsum = (s0 + s1) + (s2 + s3);
#if HAVE_PL32
      { uint2_t pr = pl32(asu(lsum), asu(lsum)); lsum = asf(pr[0]) + asf(pr[1]); }
#else
      lsum += __shfl_xor(lsum, 32, 64);
#endif
      l_run += lsum;

#pragma unroll
      for (int step = 0; step < 2; ++step) {
        const int b = 8 * step;
        half2_t x0 = pk2(st[b + 0], st[b + 1]);
        half2_t x1 = pk2(st[b + 2], st[b + 3]);
        half2_t y0 = pk2(st[b + 4], st[b + 5]);
        half2_t y1 = pk2(st[b + 6], st[b + 7]);
        H8 pa;
#if HAVE_PL32
        uint2_t sA = pl32(h2u(x0), h2u(y0));
        uint2_t sB = pl32(h2u(x1), h2u(y1));
        pa.h2[0] = u2h(sA[0]); pa.h2[1] = u2h(sB[0]);
        pa.h2[2] = u2h(sA[1]); pa.h2[3] = u2h(sB[1]);
#else
        half2_t sx0 = u2h(__shfl_xor(h2u(x0), 32, 64));
        half2_t sx1 = u2h(__shfl_xor(h2u(x1), 32, 64));
        half2_t sy0 = u2h(__shfl_xor(h2u(y0), 32, 64));
        half2_t sy1 = u2h(__shfl_xor(h2u(y1), 32, 64));
        pa.h2[0] = hi ? sy0 : x0;  pa.h2[1] = hi ? sy1 : x1;
        pa.h2[2] = hi ? y0 : sx0;  pa.h2[3] = hi ? y1 : sx1;
#endif
#pragma unroll
        for (int nt = 0; nt < 2; ++nt) {
          half8_t vf = *(const half8_t*)&Vbuf[bc][(s * 2 + step) * 1024 + nt * 256 + fb];
          acc[nt] = __builtin_amdgcn_mfma_f32_32x32x16_f16(pa.v, vf, acc[nt], 0, 0, 0);
        }
      }
    }

    bc += 1; if (bc >= 3) bc = 0;
  }

  const float invl = 1.f / l_run;
#pragma unroll
  for (int r = 0; r < 16; ++r) {
    const int qr = (r & 3) + 8 * (r >> 2) + 4 * hi;
    float il = asf(__builtin_amdgcn_ds_bpermute(qr << 2, asu(invl)));
    float* op = O + hoff + (size_t)(qbase + qr) * DDm + lo5;
    op[0]  = acc[0][r] * il;
    op[32] = acc[1][r] * il;
  }
}

extern "C" void kernel_launch(void* const* d_in, const int* in_sizes, int n_in,
                              void* d_out, int out_size, void* d_ws, size_t ws_size,
                              hipStream_t stream) {
  const float* Q = (const float*)d_in[0];
  const float* K = (const float*)d_in[1];
  const float* V = (const float*)d_in[2];
  float* O = (float*)d_out;

  const size_t n_kv   = (size_t)HH * SS * DDm;          // 4 Mi elems
  const size_t sz_pre = 2 * n_kv * sizeof(_Float16);    // 16 MiB
  const size_t sz_acc = (size_t)512 * 16384 * 4;        // 32 MiB
  const size_t sz_ml  = (size_t)512 * 512 * 4;          // 1 MiB

  if (ws_size >= sz_pre + sz_acc + sz_ml) {
    _Float16* Kh  = (_Float16*)d_ws;
    _Float16* Vth = Kh + n_kv;
    float* Pacc = (float*)((char*)d_ws + sz_pre);
    float* Pml  = (float*)((char*)d_ws + sz_pre + sz_acc);
    prepack<<<dim3(4096), dim3(256), 0, stream>>>(K, V, Kh, Vth);
    attn_split<<<dim3(512), dim3(512), 0, stream>>>(Q, Kh, Vth, Pacc, Pml);
    merge_halves<<<dim3(4096), dim3(256), 0, stream>>>(Pacc, Pml, O);
  } else if (ws_size >= sz_pre) {
    _Float16* Kh  = (_Float16*)d_ws;
    _Float16* Vth = Kh + n_kv;
    prepack<<<dim3(4096), dim3(256), 0, stream>>>(K, V, Kh, Vth);
    attn_full<<<dim3(256), dim3(512), 0, stream>>>(Q, Kh, Vth, O);
  }
}